// Round 23
// baseline (131.376 us; speedup 1.0000x reference)
//
#include <hip/hip_runtime.h>
#include <hip/hip_bf16.h>

typedef __attribute__((ext_vector_type(8))) __bf16 bf16x8;
typedef __attribute__((ext_vector_type(4))) __bf16 bf16x4;
typedef __attribute__((ext_vector_type(4))) float f32x4;

#define D_MODEL 1024
#define S_LEN   2048
#define BATCH   2
#define NH      16
#define HD      64
#define MROWS   (BATCH * S_LEN)   // 4096

#define EXP2F(x) __builtin_amdgcn_exp2f(x)

// ---------------- f32 -> bf16 convert (single f32 source) ----------------
__global__ __launch_bounds__(256) void cvt_bf16(const float* __restrict__ in,
                                                __bf16* __restrict__ out, int n4) {
    int i = blockIdx.x * 256 + threadIdx.x;
    if (i < n4) {
        float4 v = ((const float4*)in)[i];
        bf16x4 o = {(__bf16)v.x, (__bf16)v.y, (__bf16)v.z, (__bf16)v.w};
        ((bf16x4*)out)[i] = o;
    }
}

// fused x + Wq/Wk/Wv -> bf16 (one launch)
__global__ __launch_bounds__(256) void cvt_all(const float* __restrict__ x,
                                               const float* __restrict__ Wq,
                                               const float* __restrict__ Wk,
                                               const float* __restrict__ Wv,
                                               __bf16* __restrict__ xb,
                                               __bf16* __restrict__ wqkv) {
    const int nx = (MROWS * D_MODEL) / 4;     // 1048576
    const int nw = (D_MODEL * D_MODEL) / 4;   // 262144
    int i = blockIdx.x * 256 + threadIdx.x;
    const float* src;
    __bf16* dst;
    int si, di;
    if (i < nx) {
        src = x; si = i; dst = xb; di = i;
    } else {
        int k = i - nx;
        int sel = k / nw;
        si = k - sel * nw;
        src = (sel == 0) ? Wq : (sel == 1) ? Wk : Wv;
        dst = wqkv; di = k;
    }
    float4 v = ((const float4*)src)[si];
    bf16x4 o = {(__bf16)v.x, (__bf16)v.y, (__bf16)v.z, (__bf16)v.w};
    ((bf16x4*)dst)[di] = o;
}

// async global->LDS 16B (wave-uniform LDS base + lane*16)
__device__ __forceinline__ void g2l16(const void* g, __bf16* l) {
    __builtin_amdgcn_global_load_lds((const __attribute__((address_space(1))) void*)g,
                                     (__attribute__((address_space(3))) void*)l, 16, 0, 0);
}

// ---------------- Fused QKV GEMM (dbuf + counted-vmcnt, R22 skeleton) -----------
// A: bf16 [4096][1024]; W: bf16 [3072][1024] (Wq;Wk;Wv rows concatenated).
// 128x128 tile, BK=64, 4 waves (2x2), T2 XOR swizzle, grid 768 XCD-chunked.
// LDS double-buffered (64 KB, 2 blk/CU). Per K-step: issue next tile's 8
// global_load_lds; s_waitcnt vmcnt(8) waits ONLY own prior-step loads (they
// had a full step to fly); raw s_barrier => all waves' current tile staged;
// compute; raw s_barrier => cur free for restage. No vmcnt(0) drain anywhere
// in the loop (the R19 failure mode). Skeleton race-validated in R22's attn.
__global__ __launch_bounds__(256) void gemm_qkv(const __bf16* __restrict__ A,
                                                const __bf16* __restrict__ W,
                                                __bf16* __restrict__ Qb,
                                                __bf16* __restrict__ Kq,
                                                __bf16* __restrict__ VTb,
                                                float qs) {
    __shared__ __bf16 sa[2][128 * 64];  // 16 KB each
    __shared__ __bf16 sb[2][128 * 64];  // 16 KB each

    const int t    = threadIdx.x;
    const int lane = t & 63;
    const int wid  = t >> 6;
    const int lr   = lane & 15;
    const int lg   = lane >> 4;
    const int wr   = wid >> 1;
    const int wc   = wid & 1;
    const int K    = D_MODEL;

    const int bid  = blockIdx.x;
    const int swz  = (bid & 7) * 96 + (bid >> 3);
    const int m0   = (swz / 24) * 128;
    const int n0   = (swz % 24) * 128;

    const __bf16* Ab = A + (size_t)m0 * K;
    const __bf16* Wb = W + (size_t)n0 * K;

    f32x4 acc[4][4];
#pragma unroll
    for (int m = 0; m < 4; m++)
#pragma unroll
        for (int n = 0; n < 4; n++) acc[m][n] = (f32x4){0.f, 0.f, 0.f, 0.f};

    // stage tile at k0 into buffer buf (8 loads/thread: 4 A + 4 W)
    auto stage = [&](int buf, int k0) {
#pragma unroll
        for (int i = 0; i < 4; i++) {
            int ca = i * 256 + t;
            int row = ca >> 3;
            int sc  = ((ca & 7) ^ (row & 7)) * 8;
            g2l16(&Ab[(size_t)row * K + k0 + sc], &sa[buf][ca * 8]);
            g2l16(&Wb[(size_t)row * K + k0 + sc], &sb[buf][ca * 8]);
        }
    };

    stage(0, 0);

    for (int k0 = 0; k0 < K; k0 += 64) {
        const int cur = (k0 >> 6) & 1;
        const int nb  = cur ^ 1;
        // issue next tile (clamped tail restage -> uniform 8 loads/step)
        const int kn  = (k0 + 64 < K) ? k0 + 64 : k0;
        stage(nb, kn);

        // wait for OWN prior-step 8 loads (tile cur); newest 8 stay in flight
        asm volatile("s_waitcnt vmcnt(8)" ::: "memory");
        __builtin_amdgcn_sched_barrier(0);
        __builtin_amdgcn_s_barrier();          // all waves: tile cur staged
        __builtin_amdgcn_sched_barrier(0);

        bf16x8 af[4][2], bfr[4][2];
#pragma unroll
        for (int m = 0; m < 4; m++) {
            const int row = wr * 64 + m * 16 + lr;
#pragma unroll
            for (int kc = 0; kc < 2; kc++)
                af[m][kc] = *(const bf16x8*)&sa[cur][row * 64 + (((kc * 4 + lg) ^ (lr & 7)) * 8)];
        }
#pragma unroll
        for (int n = 0; n < 4; n++) {
            const int row = wc * 64 + n * 16 + lr;
#pragma unroll
            for (int kc = 0; kc < 2; kc++)
                bfr[n][kc] = *(const bf16x8*)&sb[cur][row * 64 + (((kc * 4 + lg) ^ (lr & 7)) * 8)];
        }
#pragma unroll
        for (int m = 0; m < 4; m++)
#pragma unroll
            for (int n = 0; n < 4; n++)
#pragma unroll
                for (int kc = 0; kc < 2; kc++)
                    acc[m][n] = __builtin_amdgcn_mfma_f32_16x16x32_bf16(af[m][kc], bfr[n][kc], acc[m][n], 0, 0, 0);

        // end barrier: all waves done reading cur (no vmcnt drain)
        __builtin_amdgcn_sched_barrier(0);
        __builtin_amdgcn_s_barrier();
        __builtin_amdgcn_sched_barrier(0);
    }

#pragma unroll
    for (int m = 0; m < 4; m++) {
#pragma unroll
        for (int n = 0; n < 4; n++) {
#pragma unroll
            for (int j = 0; j < 4; j++) {
                int row = m0 + wr * 64 + m * 16 + lg * 4 + j;
                int col = n0 + wc * 64 + n * 16 + lr;
                float v = acc[m][n][j];
                if (col < 1024) {
                    Qb[(size_t)row * D_MODEL + col] = (__bf16)(v * qs);
                } else if (col < 2048) {
                    Kq[(size_t)row * D_MODEL + col - 1024] = (__bf16)v;
                } else {
                    int c2 = col - 2048;
                    int b = row >> 11, s = row & 2047;
                    int h = c2 >> 6, d = c2 & 63;
                    VTb[(((size_t)(b * NH + h) * HD + d) << 11) + s] = (__bf16)v;
                }
            }
        }
    }
}

// ---------------- Output GEMM (dbuf + counted-vmcnt, 48KB -> 3 blk/CU) ----------
// 128x64 tile, BK=64, 4 waves, XCD-chunked grid 512. 6 loads/step -> vmcnt(6).
__global__ __launch_bounds__(256) void gemm_out(const __bf16* __restrict__ A,
                                                const __bf16* __restrict__ W,
                                                float* __restrict__ C,
                                                int M, int N, int K) {
    __shared__ __bf16 sa[2][128 * 64];  // 16 KB each
    __shared__ __bf16 sb[2][64 * 64];   // 8 KB each

    const int t    = threadIdx.x;
    const int lane = t & 63;
    const int wid  = t >> 6;
    const int lr   = lane & 15;
    const int lg   = lane >> 4;
    const int wr   = wid >> 1;
    const int wc   = wid & 1;

    const int bid  = blockIdx.x;
    const int swz  = (bid & 7) * 64 + (bid >> 3);
    const int m0   = (swz / 16) * 128;
    const int n0   = (swz % 16) * 64;

    const __bf16* Ab = A + (size_t)m0 * K;
    const __bf16* Wb = W + (size_t)n0 * K;

    f32x4 acc[4][2];
#pragma unroll
    for (int m = 0; m < 4; m++)
#pragma unroll
        for (int n = 0; n < 2; n++) acc[m][n] = (f32x4){0.f, 0.f, 0.f, 0.f};

    // stage tile at k0 into buffer buf (6 loads/thread: 4 A + 2 W)
    auto stage = [&](int buf, int k0) {
#pragma unroll
        for (int i = 0; i < 4; i++) {
            int ca = i * 256 + t;
            int row = ca >> 3;
            int sc  = ((ca & 7) ^ (row & 7)) * 8;
            g2l16(&Ab[(size_t)row * K + k0 + sc], &sa[buf][ca * 8]);
        }
#pragma unroll
        for (int i = 0; i < 2; i++) {
            int ca = i * 256 + t;
            int row = ca >> 3;
            int sc  = ((ca & 7) ^ (row & 7)) * 8;
            g2l16(&Wb[(size_t)row * K + k0 + sc], &sb[buf][ca * 8]);
        }
    };

    stage(0, 0);

    for (int k0 = 0; k0 < K; k0 += 64) {
        const int cur = (k0 >> 6) & 1;
        const int nb  = cur ^ 1;
        const int kn  = (k0 + 64 < K) ? k0 + 64 : k0;
        stage(nb, kn);

        asm volatile("s_waitcnt vmcnt(6)" ::: "memory");
        __builtin_amdgcn_sched_barrier(0);
        __builtin_amdgcn_s_barrier();
        __builtin_amdgcn_sched_barrier(0);

        bf16x8 af[4][2], bfr[2][2];
#pragma unroll
        for (int m = 0; m < 4; m++) {
            const int row = wr * 64 + m * 16 + lr;
#pragma unroll
            for (int kc = 0; kc < 2; kc++)
                af[m][kc] = *(const bf16x8*)&sa[cur][row * 64 + (((kc * 4 + lg) ^ (lr & 7)) * 8)];
        }
#pragma unroll
        for (int n = 0; n < 2; n++) {
            const int row = wc * 32 + n * 16 + lr;
#pragma unroll
            for (int kc = 0; kc < 2; kc++)
                bfr[n][kc] = *(const bf16x8*)&sb[cur][row * 64 + (((kc * 4 + lg) ^ (lr & 7)) * 8)];
        }
#pragma unroll
        for (int m = 0; m < 4; m++)
#pragma unroll
            for (int n = 0; n < 2; n++)
#pragma unroll
                for (int kc = 0; kc < 2; kc++)
                    acc[m][n] = __builtin_amdgcn_mfma_f32_16x16x32_bf16(af[m][kc], bfr[n][kc], acc[m][n], 0, 0, 0);

        __builtin_amdgcn_sched_barrier(0);
        __builtin_amdgcn_s_barrier();
        __builtin_amdgcn_sched_barrier(0);
    }

#pragma unroll
    for (int m = 0; m < 4; m++)
#pragma unroll
        for (int n = 0; n < 2; n++)
#pragma unroll
            for (int j = 0; j < 4; j++) {
                int row = m0 + wr * 64 + m * 16 + lg * 4 + j;
                int col = n0 + wc * 32 + n * 16 + lr;
                C[(size_t)row * N + col] = acc[m][n][j];
            }
}

// ---------------- Causal flash attention (8 waves, counted-vmcnt; R22 exact) ----
__global__ __launch_bounds__(512) void attn_fwd(const __bf16* __restrict__ Q,
                                                const __bf16* __restrict__ Kb,
                                                const __bf16* __restrict__ VT,
                                                __bf16* __restrict__ O) {
    __shared__ __bf16 kt[2][64 * 64];   // 8KB each, swizzled
    __shared__ __bf16 vt[2][64 * 64];
    __shared__ __bf16 pt[8][16][64];    // wave-private P [q16][kv64], XOR-swizzled

    const int t    = threadIdx.x;       // 0..511
    const int lane = t & 63;
    const int wid  = t >> 6;            // 0..7
    const int lr   = lane & 15;
    const int lg   = lane >> 4;
    const int bid  = blockIdx.x;
    const int qb   = 15 - (bid >> 5);   // 128-row q tile, heaviest first
    const int bh   = bid & 31;
    const int b    = bh >> 4;
    const int h    = bh & 15;
    const int col  = h * HD;

    const size_t qrow = (size_t)b * S_LEN + qb * 128 + wid * 16;
    const int qg = qb * 128 + wid * 16 + lr;         // this lane's q (swapped layout)
    const __bf16* Kbase = Kb + (size_t)b * S_LEN * D_MODEL + col;
    const __bf16* Vbase = VT + (size_t)bh * HD * S_LEN;
    const int pswz = (lr & 7) * 8;                   // P-buffer XOR swizzle term

    // staging geometry: 512 chunks of 16B per tile, 1 per thread per tile
    const int ca0 = t;
    const int r0 = ca0 >> 3, s0 = ((ca0 & 7) ^ (r0 & 7)) * 8;

    bf16x8 qf[2];
#pragma unroll
    for (int c = 0; c < 2; c++)
        qf[c] = *(const bf16x8*)&Q[(qrow + lr) * D_MODEL + col + c * 32 + lg * 8];

    f32x4 o[4];
#pragma unroll
    for (int n = 0; n < 4; n++) o[n] = (f32x4){0.f, 0.f, 0.f, 0.f};
    float psum = 0.f;   // partial row-sum for q=qg

    const int nkv = 2 * qb + 2;   // 64-wide kv tiles covering q <= qb*128+127

    // prologue: stage tile 0 into buffer 0 (2 loads/thread)
    g2l16(&Kbase[(size_t)r0 * D_MODEL + s0], &kt[0][ca0 * 8]);
    g2l16(&Vbase[(size_t)r0 * S_LEN + s0],   &vt[0][ca0 * 8]);

    for (int kvt = 0; kvt < nkv; kvt++) {
        const int kv0 = kvt * 64;
        const int cur = kvt & 1;
        const int nb  = cur ^ 1;

        // issue next tile's staging (clamped at tail -> uniform 2 loads/step)
        {
            const int kvn = (kvt + 1 < nkv) ? kvt + 1 : nkv - 1;
            const int kv1 = kvn * 64;
            g2l16(&Kbase[(size_t)(kv1 + r0) * D_MODEL + s0], &kt[nb][ca0 * 8]);
            g2l16(&Vbase[(size_t)r0 * S_LEN + kv1 + s0],     &vt[nb][ca0 * 8]);
        }

        // wait for OWN prior-step staging (tile kvt) only; newest 2 stay in flight
        asm volatile("s_waitcnt vmcnt(2)" ::: "memory");
        __builtin_amdgcn_sched_barrier(0);
        __builtin_amdgcn_s_barrier();          // all waves: tile kvt fully staged
        __builtin_amdgcn_sched_barrier(0);

        // S^T = K @ Q^T (swapped operands)
        f32x4 s[4];
        __builtin_amdgcn_s_setprio(1);
#pragma unroll
        for (int tt = 0; tt < 4; tt++) {
            s[tt] = (f32x4){0.f, 0.f, 0.f, 0.f};
#pragma unroll
            for (int c = 0; c < 2; c++) {
                const int row = tt * 16 + lr;
                bf16x8 kf = *(const bf16x8*)&kt[cur][row * 64 + (((c * 4 + lg) ^ (lr & 7)) * 8)];
                s[tt] = __builtin_amdgcn_mfma_f32_16x16x32_bf16(kf, qf[c], s[tt], 0, 0, 0);
            }
        }
        __builtin_amdgcn_s_setprio(0);

        // causal mask whenever this kv tile can exceed this lane's q
        if (kv0 + 63 > qg) {
#pragma unroll
            for (int tt = 0; tt < 4; tt++) {
                int kg = kv0 + tt * 16 + lg * 4;
#pragma unroll
                for (int j = 0; j < 4; j++)
                    if (kg + j > qg) s[tt][j] = -1e30f;
            }
        }

        // P = exp2(S); scalar psum; packed b64 writes (4 per lane)
#pragma unroll
        for (int tt = 0; tt < 4; tt++) {
            float p0 = EXP2F(s[tt][0]), p1 = EXP2F(s[tt][1]);
            float p2 = EXP2F(s[tt][2]), p3 = EXP2F(s[tt][3]);
            psum += (p0 + p1) + (p2 + p3);
            bf16x4 pw = {(__bf16)p0, (__bf16)p1, (__bf16)p2, (__bf16)p3};
            *(bf16x4*)&pt[wid][lr][(tt * 16 + lg * 4) ^ pswz] = pw;
        }

        // in-wave fence: P ds_writes complete before pa ds_reads
        asm volatile("s_waitcnt lgkmcnt(0)" ::: "memory");
        __builtin_amdgcn_sched_barrier(0);

        // O += P @ V from LDS (pa: row q=lr, kv chunk c*32+lg*8, swizzled)
        __builtin_amdgcn_s_setprio(1);
#pragma unroll
        for (int c = 0; c < 2; c++) {
            bf16x8 pa = *(const bf16x8*)&pt[wid][lr][(c * 32 + lg * 8) ^ pswz];
#pragma unroll
            for (int n = 0; n < 4; n++) {
                const int d = n * 16 + lr;
                bf16x8 vf = *(const bf16x8*)&vt[cur][d * 64 + (((c * 4 + lg) ^ (lr & 7)) * 8)];
                o[n] = __builtin_amdgcn_mfma_f32_16x16x32_bf16(pa, vf, o[n], 0, 0, 0);
            }
        }
        __builtin_amdgcn_s_setprio(0);

        // end barrier: all waves done reading cur (no vmcnt drain)
        __builtin_amdgcn_sched_barrier(0);
        __builtin_amdgcn_s_barrier();
        __builtin_amdgcn_sched_barrier(0);
    }

    // final l reduce: psum holds partials for q=qg; sum across the 4 lg groups
    psum += __shfl_xor(psum, 16, 64);
    psum += __shfl_xor(psum, 32, 64);
    float inv = 1.0f / psum;
    // redistribute to O's row layout (row q = lg*4+j): fetch inv from lane (lg*4+j)
    float invj[4];
#pragma unroll
    for (int j = 0; j < 4; j++) invj[j] = __shfl(inv, lg * 4 + j, 64);

    // normalize + store
#pragma unroll
    for (int n = 0; n < 4; n++) {
#pragma unroll
        for (int j = 0; j < 4; j++) {
            float val = o[n][j] * invj[j];
            O[(qrow + lg * 4 + j) * D_MODEL + col + n * 16 + lr] = (__bf16)val;
        }
    }
}

extern "C" void kernel_launch(void* const* d_in, const int* in_sizes, int n_in,
                              void* d_out, int out_size, void* d_ws, size_t ws_size,
                              hipStream_t stream) {
    const float* x  = (const float*)d_in[0];
    const float* Wq = (const float*)d_in[1];
    const float* Wk = (const float*)d_in[2];
    const float* Wv = (const float*)d_in[3];
    const float* Wo = (const float*)d_in[4];
    float* out = (float*)d_out;

    const size_t XE = (size_t)MROWS * D_MODEL;      // 4M elems
    const size_t WE = (size_t)D_MODEL * D_MODEL;    // 1M elems
    // Workspace: exactly 32 MB (proven safe).
    __bf16* xb  = (__bf16*)d_ws;   // 8 MB; reused as attention output later
    __bf16* Qb  = xb + XE;         // 8 MB; Wo-bf16 scratch after attn
    __bf16* Kq  = Qb + XE;         // 8 MB
    __bf16* VTb = Kq + XE;         // 8 MB
    __bf16* AO  = xb;              // alias: x dead after QKV GEMM

    // bf16 weight scratch inside d_out (dead until final GEMM overwrites it).
    __bf16* wqkv = (__bf16*)d_out;             // 6 MB, [3072][1024]
    __bf16* wob  = Qb;                         // Wo bf16 -> dead Qb after attn

    const int ncv = (int)(XE / 4 + 3 * WE / 4);
    cvt_all<<<(ncv + 255) / 256, 256, 0, stream>>>(x, Wq, Wk, Wv, xb, wqkv);

    // Q projection pre-scaled by log2(e)/sqrt(HD) (exp2-domain softmax)
    const float qs = 0.125f * 1.44269504088896340736f;
    gemm_qkv<<<768, 256, 0, stream>>>(xb, wqkv, Qb, Kq, VTb, qs);

    attn_fwd<<<512, 512, 0, stream>>>(Qb, Kq, VTb, AO);

    // Qb dead now; convert Wo into it and run the output projection in bf16.
    cvt_bf16<<<(int)(WE / 4 / 256), 256, 0, stream>>>(Wo, wob, (int)(WE / 4));
    gemm_out<<<512, 256, 0, stream>>>(AO, wob, out, MROWS, D_MODEL, D_MODEL);
}

// Round 24
// 110.710 us; speedup vs baseline: 1.1867x; 1.1867x over previous
//
#include <hip/hip_runtime.h>
#include <hip/hip_bf16.h>

typedef __attribute__((ext_vector_type(8))) __bf16 bf16x8;
typedef __attribute__((ext_vector_type(4))) __bf16 bf16x4;
typedef __attribute__((ext_vector_type(4))) float f32x4;

#define D_MODEL 1024
#define S_LEN   2048
#define BATCH   2
#define NH      16
#define HD      64
#define MROWS   (BATCH * S_LEN)   // 4096

#define EXP2F(x) __builtin_amdgcn_exp2f(x)

// fused x + Wq/Wk/Wv -> bf16 (one launch)
__global__ __launch_bounds__(256) void cvt_all(const float* __restrict__ x,
                                               const float* __restrict__ Wq,
                                               const float* __restrict__ Wk,
                                               const float* __restrict__ Wv,
                                               __bf16* __restrict__ xb,
                                               __bf16* __restrict__ wqkv) {
    const int nx = (MROWS * D_MODEL) / 4;     // 1048576
    const int nw = (D_MODEL * D_MODEL) / 4;   // 262144
    int i = blockIdx.x * 256 + threadIdx.x;
    const float* src;
    __bf16* dst;
    int si, di;
    if (i < nx) {
        src = x; si = i; dst = xb; di = i;
    } else {
        int k = i - nx;
        int sel = k / nw;
        si = k - sel * nw;
        src = (sel == 0) ? Wq : (sel == 1) ? Wk : Wv;
        dst = wqkv; di = k;
    }
    float4 v = ((const float4*)src)[si];
    bf16x4 o = {(__bf16)v.x, (__bf16)v.y, (__bf16)v.z, (__bf16)v.w};
    ((bf16x4*)dst)[di] = o;
}

// async global->LDS 16B (wave-uniform LDS base + lane*16)
__device__ __forceinline__ void g2l16(const void* g, __bf16* l) {
    __builtin_amdgcn_global_load_lds((const __attribute__((address_space(1))) void*)g,
                                     (__attribute__((address_space(3))) void*)l, 16, 0, 0);
}

// ---------------- Fused QKV GEMM (R20 exact: R12 structure + XCD swizzle) -------
// 128x128 tile, BK=64, 4 waves, 32KB LDS, T2 XOR swizzle, grid 768 XCD-chunked.
__global__ __launch_bounds__(256) void gemm_qkv(const __bf16* __restrict__ A,
                                                const __bf16* __restrict__ W,
                                                __bf16* __restrict__ Qb,
                                                __bf16* __restrict__ Kq,
                                                __bf16* __restrict__ VTb,
                                                float qs) {
    __shared__ __bf16 sa[128 * 64];  // 16 KB
    __shared__ __bf16 sb[128 * 64];  // 16 KB

    const int t    = threadIdx.x;
    const int lane = t & 63;
    const int wid  = t >> 6;
    const int lr   = lane & 15;
    const int lg   = lane >> 4;
    const int wr   = wid >> 1;
    const int wc   = wid & 1;
    const int K    = D_MODEL;

    const int bid  = blockIdx.x;
    const int swz  = (bid & 7) * 96 + (bid >> 3);
    const int m0   = (swz / 24) * 128;
    const int n0   = (swz % 24) * 128;

    const __bf16* Ab = A + (size_t)m0 * K;
    const __bf16* Wb = W + (size_t)n0 * K;

    f32x4 acc[4][4];
#pragma unroll
    for (int m = 0; m < 4; m++)
#pragma unroll
        for (int n = 0; n < 4; n++) acc[m][n] = (f32x4){0.f, 0.f, 0.f, 0.f};

    for (int k0 = 0; k0 < K; k0 += 64) {
#pragma unroll
        for (int i = 0; i < 4; i++) {
            int ca = i * 256 + t;
            int row = ca >> 3;
            int sc  = ((ca & 7) ^ (row & 7)) * 8;
            g2l16(&Ab[(size_t)row * K + k0 + sc], &sa[ca * 8]);
            g2l16(&Wb[(size_t)row * K + k0 + sc], &sb[ca * 8]);
        }
        __syncthreads();

        bf16x8 af[4][2], bfr[4][2];
#pragma unroll
        for (int m = 0; m < 4; m++) {
            const int row = wr * 64 + m * 16 + lr;
#pragma unroll
            for (int kc = 0; kc < 2; kc++)
                af[m][kc] = *(const bf16x8*)&sa[row * 64 + (((kc * 4 + lg) ^ (lr & 7)) * 8)];
        }
#pragma unroll
        for (int n = 0; n < 4; n++) {
            const int row = wc * 64 + n * 16 + lr;
#pragma unroll
            for (int kc = 0; kc < 2; kc++)
                bfr[n][kc] = *(const bf16x8*)&sb[row * 64 + (((kc * 4 + lg) ^ (lr & 7)) * 8)];
        }
#pragma unroll
        for (int m = 0; m < 4; m++)
#pragma unroll
            for (int n = 0; n < 4; n++)
#pragma unroll
                for (int kc = 0; kc < 2; kc++)
                    acc[m][n] = __builtin_amdgcn_mfma_f32_16x16x32_bf16(af[m][kc], bfr[n][kc], acc[m][n], 0, 0, 0);
        __syncthreads();
    }

#pragma unroll
    for (int m = 0; m < 4; m++) {
#pragma unroll
        for (int n = 0; n < 4; n++) {
#pragma unroll
            for (int j = 0; j < 4; j++) {
                int row = m0 + wr * 64 + m * 16 + lg * 4 + j;
                int col = n0 + wc * 64 + n * 16 + lr;
                float v = acc[m][n][j];
                if (col < 1024) {
                    Qb[(size_t)row * D_MODEL + col] = (__bf16)(v * qs);
                } else if (col < 2048) {
                    Kq[(size_t)row * D_MODEL + col - 1024] = (__bf16)v;
                } else {
                    int c2 = col - 2048;
                    int b = row >> 11, s = row & 2047;
                    int h = c2 >> 6, d = c2 & 63;
                    VTb[(((size_t)(b * NH + h) * HD + d) << 11) + s] = (__bf16)v;
                }
            }
        }
    }
}

// ---------------- Output GEMM (R20 structure; W = f32 Wo, cvt fused in-stage) ---
// 128x64 tile, BK=64, 4 waves, XCD-chunked grid 512. A via g2l16 (swizzled
// source); W tile (64x64) reg-staged f32 -> bf16 -> swizzled ds_write (R4/R6
// proven pattern). Removes the separate Wo cvt kernel + launch gap.
__global__ __launch_bounds__(256) void gemm_out(const __bf16* __restrict__ A,
                                                const float* __restrict__ W,
                                                float* __restrict__ C,
                                                int M, int N, int K) {
    __shared__ __bf16 sa[128 * 64];  // 16 KB
    __shared__ __bf16 sb[64 * 64];   // 8 KB

    const int t    = threadIdx.x;
    const int lane = t & 63;
    const int wid  = t >> 6;
    const int lr   = lane & 15;
    const int lg   = lane >> 4;
    const int wr   = wid >> 1;
    const int wc   = wid & 1;

    const int bid  = blockIdx.x;
    const int swz  = (bid & 7) * 64 + (bid >> 3);
    const int m0   = (swz / 16) * 128;
    const int n0   = (swz % 16) * 64;

    const __bf16* Ab = A + (size_t)m0 * K;
    const float*  Wb = W + (size_t)n0 * K;
    // this thread's W-stage coords (2 chunks: rows t>>2 pattern over 64x64)
    const int wca0 = t, wca1 = t + 256;

    f32x4 acc[4][2];
#pragma unroll
    for (int m = 0; m < 4; m++)
#pragma unroll
        for (int n = 0; n < 2; n++) acc[m][n] = (f32x4){0.f, 0.f, 0.f, 0.f};

    for (int k0 = 0; k0 < K; k0 += 64) {
#pragma unroll
        for (int i = 0; i < 4; i++) {
            int ca = i * 256 + t;
            int row = ca >> 3;
            int sc  = ((ca & 7) ^ (row & 7)) * 8;
            g2l16(&Ab[(size_t)row * K + k0 + sc], &sa[ca * 8]);
        }
        // W tile: 64 rows x 64 cols f32, 2 chunks of 8 floats per thread,
        // cvt to bf16 and write to the XOR-swizzled LDS slot.
#pragma unroll
        for (int i = 0; i < 2; i++) {
            int ca  = (i == 0) ? wca0 : wca1;
            int row = ca >> 3;
            int c8  = (ca & 7) * 8;
            const float4 w0 = *(const float4*)&Wb[(size_t)row * K + k0 + c8];
            const float4 w1 = *(const float4*)&Wb[(size_t)row * K + k0 + c8 + 4];
            bf16x8 v = {(__bf16)w0.x, (__bf16)w0.y, (__bf16)w0.z, (__bf16)w0.w,
                        (__bf16)w1.x, (__bf16)w1.y, (__bf16)w1.z, (__bf16)w1.w};
            *(bf16x8*)&sb[row * 64 + (((ca & 7) ^ (row & 7)) * 8)] = v;
        }
        __syncthreads();

        bf16x8 af[4][2], bfr[2][2];
#pragma unroll
        for (int m = 0; m < 4; m++) {
            const int row = wr * 64 + m * 16 + lr;
#pragma unroll
            for (int kc = 0; kc < 2; kc++)
                af[m][kc] = *(const bf16x8*)&sa[row * 64 + (((kc * 4 + lg) ^ (lr & 7)) * 8)];
        }
#pragma unroll
        for (int n = 0; n < 2; n++) {
            const int row = wc * 32 + n * 16 + lr;
#pragma unroll
            for (int kc = 0; kc < 2; kc++)
                bfr[n][kc] = *(const bf16x8*)&sb[row * 64 + (((kc * 4 + lg) ^ (lr & 7)) * 8)];
        }
#pragma unroll
        for (int m = 0; m < 4; m++)
#pragma unroll
            for (int n = 0; n < 2; n++)
#pragma unroll
                for (int kc = 0; kc < 2; kc++)
                    acc[m][n] = __builtin_amdgcn_mfma_f32_16x16x32_bf16(af[m][kc], bfr[n][kc], acc[m][n], 0, 0, 0);
        __syncthreads();
    }

#pragma unroll
    for (int m = 0; m < 4; m++)
#pragma unroll
        for (int n = 0; n < 2; n++)
#pragma unroll
            for (int j = 0; j < 4; j++) {
                int row = m0 + wr * 64 + m * 16 + lg * 4 + j;
                int col = n0 + wc * 32 + n * 16 + lr;
                C[(size_t)row * N + col] = acc[m][n][j];
            }
}

// ---------------- Causal flash attention (R20/R12 exact: K+V staged, 4-wave) ----
// No-max exp2 softmax, deferred l. Swapped QK^T (lane holds q=lr lane-local),
// packed b64 P-writes into XOR-swizzled pt. Grid 1024 (R9/R11 lesson: never
// shrink the grid), K AND V LDS-staged (R5/R13 lesson: never read V direct).
__global__ __launch_bounds__(256) void attn_fwd(const __bf16* __restrict__ Q,
                                                const __bf16* __restrict__ Kb,
                                                const __bf16* __restrict__ VT,
                                                __bf16* __restrict__ O) {
    __shared__ __bf16 kt[2][64 * 64];   // 8KB each, swizzled
    __shared__ __bf16 vt[2][64 * 64];
    __shared__ __bf16 pt[4][16][64];    // wave-private P [q16][kv64], XOR-swizzled

    const int t    = threadIdx.x;
    const int lane = t & 63;
    const int wid  = t >> 6;
    const int lr   = lane & 15;
    const int lg   = lane >> 4;
    const int bid  = blockIdx.x;
    const int qb   = 31 - (bid >> 5);
    const int bh   = bid & 31;
    const int b    = bh >> 4;
    const int h    = bh & 15;
    const int col  = h * HD;

    const size_t qrow = (size_t)b * S_LEN + qb * 64 + wid * 16;
    const int qg = qb * 64 + wid * 16 + lr;          // this lane's q (swapped layout)
    const __bf16* Kbase = Kb + (size_t)b * S_LEN * D_MODEL + col;
    const __bf16* Vbase = VT + (size_t)bh * HD * S_LEN;
    const int pswz = (lr & 7) * 8;                   // P-buffer XOR swizzle term

    // staging geometry: 512 chunks of 16B per tile, 2 per thread per tile
    const int ca0 = t, ca1 = t + 256;
    const int r0 = ca0 >> 3, s0 = ((ca0 & 7) ^ (r0 & 7)) * 8;
    const int r1 = ca1 >> 3, s1 = ((ca1 & 7) ^ (r1 & 7)) * 8;

    bf16x8 qf[2];
#pragma unroll
    for (int c = 0; c < 2; c++)
        qf[c] = *(const bf16x8*)&Q[(qrow + lr) * D_MODEL + col + c * 32 + lg * 8];

    f32x4 o[4];
#pragma unroll
    for (int n = 0; n < 4; n++) o[n] = (f32x4){0.f, 0.f, 0.f, 0.f};
    float psum = 0.f;   // partial row-sum for q=lr (this lane's 16 kv-slots/step)

    // prologue: stage tile 0 into buffer 0
    g2l16(&Kbase[(size_t)r0 * D_MODEL + s0], &kt[0][ca0 * 8]);
    g2l16(&Kbase[(size_t)r1 * D_MODEL + s1], &kt[0][ca1 * 8]);
    g2l16(&Vbase[(size_t)r0 * S_LEN + s0],   &vt[0][ca0 * 8]);
    g2l16(&Vbase[(size_t)r1 * S_LEN + s1],   &vt[0][ca1 * 8]);
    __syncthreads();

    for (int kvt = 0; kvt <= qb; kvt++) {
        const int kv0 = kvt * 64;
        const int cur = kvt & 1;
        const bool diag = (kvt == qb);

        // issue next tile's staging into the other buffer
        if (kvt < qb) {
            const int nb = cur ^ 1;
            const int kv1 = kv0 + 64;
            g2l16(&Kbase[(size_t)(kv1 + r0) * D_MODEL + s0], &kt[nb][ca0 * 8]);
            g2l16(&Kbase[(size_t)(kv1 + r1) * D_MODEL + s1], &kt[nb][ca1 * 8]);
            g2l16(&Vbase[(size_t)r0 * S_LEN + kv1 + s0],     &vt[nb][ca0 * 8]);
            g2l16(&Vbase[(size_t)r1 * S_LEN + kv1 + s1],     &vt[nb][ca1 * 8]);
        }

        // S^T = K @ Q^T (swapped operands; frag loads identical to non-swapped)
        f32x4 s[4];
        __builtin_amdgcn_s_setprio(1);
#pragma unroll
        for (int tt = 0; tt < 4; tt++) {
            s[tt] = (f32x4){0.f, 0.f, 0.f, 0.f};
#pragma unroll
            for (int c = 0; c < 2; c++) {
                const int row = tt * 16 + lr;
                bf16x8 kf = *(const bf16x8*)&kt[cur][row * 64 + (((c * 4 + lg) ^ (lr & 7)) * 8)];
                s[tt] = __builtin_amdgcn_mfma_f32_16x16x32_bf16(kf, qf[c], s[tt], 0, 0, 0);
            }
        }
        __builtin_amdgcn_s_setprio(0);

        // causal mask on diagonal tile: lane holds kv = kv0+tt*16+lg*4+j, q = qg
        if (diag) {
#pragma unroll
            for (int tt = 0; tt < 4; tt++) {
                int kg = kv0 + tt * 16 + lg * 4;
#pragma unroll
                for (int j = 0; j < 4; j++)
                    if (kg + j > qg) s[tt][j] = -1e30f;
            }
        }

        // P = exp2(S); scalar psum; packed b64 writes (4 per lane)
#pragma unroll
        for (int tt = 0; tt < 4; tt++) {
            float p0 = EXP2F(s[tt][0]), p1 = EXP2F(s[tt][1]);
            float p2 = EXP2F(s[tt][2]), p3 = EXP2F(s[tt][3]);
            psum += (p0 + p1) + (p2 + p3);
            bf16x4 pw = {(__bf16)p0, (__bf16)p1, (__bf16)p2, (__bf16)p3};
            *(bf16x4*)&pt[wid][lr][(tt * 16 + lg * 4) ^ pswz] = pw;
        }

        // in-wave fence: P ds_writes complete before pa ds_reads
        asm volatile("s_waitcnt lgkmcnt(0)" ::: "memory");
        __builtin_amdgcn_sched_barrier(0);

        // O += P @ V from LDS (pa: row q=lr, kv chunk c*32+lg*8, swizzled)
        __builtin_amdgcn_s_setprio(1);
#pragma unroll
        for (int c = 0; c < 2; c++) {
            bf16x8 pa = *(const bf16x8*)&pt[wid][lr][(c * 32 + lg * 8) ^ pswz];
#pragma unroll
            for (int n = 0; n < 4; n++) {
                const int d = n * 16 + lr;
                bf16x8 vf = *(const bf16x8*)&vt[cur][d * 64 + (((c * 4 + lg) ^ (lr & 7)) * 8)];
                o[n] = __builtin_amdgcn_mfma_f32_16x16x32_bf16(pa, vf, o[n], 0, 0, 0);
            }
        }
        __builtin_amdgcn_s_setprio(0);

        // one barrier per kv-step (drains stage vmcnt + guards cur reuse)
        __syncthreads();
    }

    // final l reduce: psum holds partials for q=lr; sum across the 4 lg groups
    psum += __shfl_xor(psum, 16, 64);
    psum += __shfl_xor(psum, 32, 64);
    float inv = 1.0f / psum;
    // redistribute to O's row layout (row q = lg*4+j): fetch inv from lane (lg*4+j)
    float invj[4];
#pragma unroll
    for (int j = 0; j < 4; j++) invj[j] = __shfl(inv, lg * 4 + j, 64);

    // normalize + store
#pragma unroll
    for (int n = 0; n < 4; n++) {
#pragma unroll
        for (int j = 0; j < 4; j++) {
            float val = o[n][j] * invj[j];
            O[(qrow + lg * 4 + j) * D_MODEL + col + n * 16 + lr] = (__bf16)val;
        }
    }
}

extern "C" void kernel_launch(void* const* d_in, const int* in_sizes, int n_in,
                              void* d_out, int out_size, void* d_ws, size_t ws_size,
                              hipStream_t stream) {
    const float* x  = (const float*)d_in[0];
    const float* Wq = (const float*)d_in[1];
    const float* Wk = (const float*)d_in[2];
    const float* Wv = (const float*)d_in[3];
    const float* Wo = (const float*)d_in[4];
    float* out = (float*)d_out;

    const size_t XE = (size_t)MROWS * D_MODEL;      // 4M elems
    const size_t WE = (size_t)D_MODEL * D_MODEL;    // 1M elems
    // Workspace: exactly 32 MB (proven safe).
    __bf16* xb  = (__bf16*)d_ws;   // 8 MB; reused as attention output later
    __bf16* Qb  = xb + XE;         // 8 MB
    __bf16* Kq  = Qb + XE;         // 8 MB
    __bf16* VTb = Kq + XE;         // 8 MB
    __bf16* AO  = xb;              // alias: x dead after QKV GEMM

    // bf16 weight scratch inside d_out (dead until final GEMM overwrites it).
    __bf16* wqkv = (__bf16*)d_out;             // 6 MB, [3072][1024]

    const int ncv = (int)(XE / 4 + 3 * WE / 4);
    cvt_all<<<(ncv + 255) / 256, 256, 0, stream>>>(x, Wq, Wk, Wv, xb, wqkv);

    // Q projection pre-scaled by log2(e)/sqrt(HD) (exp2-domain softmax)
    const float qs = 0.125f * 1.44269504088896340736f;
    gemm_qkv<<<768, 256, 0, stream>>>(xb, wqkv, Qb, Kq, VTb, qs);

    attn_fwd<<<1024, 256, 0, stream>>>(Qb, Kq, VTb, AO);

    // Output projection reads Wo as f32 directly (cvt fused into staging).
    gemm_out<<<512, 256, 0, stream>>>(AO, Wo, out, MROWS, D_MODEL, D_MODEL);
}